// Round 8
// baseline (282.375 us; speedup 1.0000x reference)
//
#include <hip/hip_runtime.h>

// MHA fwd: B=4, S=2048, D_IN=D_OUT=1024, H=16, HD=64. fp32 in / fp32 out.
// R18 = R17 with attn occupancy/balance rework:
//   - grid 1024 blocks (one per (qt,bh)), longest-first (qt=15-x), XCD-aware
//     decode (same bh -> same bid%8 -> same XCD L2; K/V becomes L2-resident).
//   - LDS 55.3->45KB (sP halved: P-store/PV per h2 sequentially, wave-private)
//     -> 3 blocks/CU via __launch_bounds__(256,3); 12 waves/CU latency hiding.
//   - everything else unchanged from R17 (static-max softmax, MFMA-l, sP quad
//     swizzle, dbuf K/V 1-barrier, T14 prefetch, V-frag hoist, setprio, fused
//     prep, V written transposed by gemm_qkv).

typedef float  f32x4  __attribute__((ext_vector_type(4)));
typedef __bf16 bf16x8 __attribute__((ext_vector_type(8)));
typedef __bf16 bf16x4 __attribute__((ext_vector_type(4)));

#define AS(n) __attribute__((address_space(n)))

__device__ __forceinline__ void gload16(const void* g, void* l) {
    __builtin_amdgcn_global_load_lds((const AS(1) void*)g, (AS(3) void*)l, 16, 0, 0);
}

__device__ __forceinline__ f32x4 mfma16(bf16x8 a, bf16x8 b, f32x4 c) {
    return __builtin_amdgcn_mfma_f32_16x16x32_bf16(a, b, c, 0, 0, 0);
}

// ---------------------------------------------------------------- prep: x->bf16 + W transpose
__global__ void prep_kernel(const float4* __restrict__ x, __bf16* __restrict__ xb,
                            const float* __restrict__ Wq, const float* __restrict__ Wk,
                            const float* __restrict__ Wv, const float* __restrict__ Wo,
                            __bf16* __restrict__ wqkvt, __bf16* __restrict__ wot) {
    __shared__ float tile[32][33];
    int bid = blockIdx.x, tid = threadIdx.x;
    if (bid < 8192) {
        int t = bid * 256 + tid;
        float4 v = x[t];
        bf16x4 o = { (__bf16)v.x, (__bf16)v.y, (__bf16)v.z, (__bf16)v.w };
        ((bf16x4*)xb)[t] = o;
        return;
    }
    int idx = bid - 8192;                 // 0..4095
    int z = idx >> 10, rest = idx & 1023;
    int by = rest >> 5, bx = rest & 31;
    const float* src; __bf16* dst;
    if (z == 0)      { src = Wq; dst = wqkvt; }
    else if (z == 1) { src = Wk; dst = wqkvt + 1048576; }
    else if (z == 2) { src = Wv; dst = wqkvt + 2097152; }
    else             { src = Wo; dst = wot; }
    int tx = tid & 31, ty = tid >> 5;     // 32 x 8
    int xcol = bx * 32 + tx;
    int y0 = by * 32;
#pragma unroll
    for (int i = ty; i < 32; i += 8) tile[i][tx] = src[(size_t)(y0 + i) * 1024 + xcol];
    __syncthreads();
    int xo = by * 32 + tx;                // col = k
    int yo0 = bx * 32;                    // row = n
#pragma unroll
    for (int i = ty; i < 32; i += 8) dst[(size_t)(yo0 + i) * 1024 + xo] = (__bf16)tile[tx][i];
}

// ---------------------------------------------------------------- QKV GEMM (MFMA)
// Writes Q(scaled)/K as [B,H,S,HD]; V directly TRANSPOSED as Vt[B,H,HD,S].
__global__ __launch_bounds__(256, 2) void gemm_qkv_kernel(
        const __bf16* __restrict__ A, const __bf16* __restrict__ Bt,
        __bf16* __restrict__ Qp, __bf16* __restrict__ Kp, __bf16* __restrict__ Vt) {
    __shared__ __bf16 lA[128 * 32];
    __shared__ __bf16 lB[128 * 32];
    __shared__ __bf16 lT[128 * 136];   // V transpose bounce [n_local][m_local]
    int tid = threadIdx.x;
    int m0 = blockIdx.x * 128, n0 = blockIdx.y * 128;
    int w = tid >> 6, lane = tid & 63, quad = lane >> 4, l15 = lane & 15;
    int wm = (w & 1) * 64, wn = (w >> 1) * 64;
    f32x4 acc[4][4] = {};
    int rowS = tid >> 2, kc = tid & 3;
    const __bf16* Abase = A + (size_t)m0 * 1024;
    const __bf16* Bbase = Bt + (size_t)n0 * 1024;
    for (int kt = 0; kt < 32; kt++) {
        int k0 = kt * 32;
        gload16(Abase + (size_t)rowS * 1024 + k0 + kc * 8,        &lA[tid * 8]);
        gload16(Abase + (size_t)(rowS + 64) * 1024 + k0 + kc * 8, &lA[(tid + 256) * 8]);
        gload16(Bbase + (size_t)rowS * 1024 + k0 + kc * 8,        &lB[tid * 8]);
        gload16(Bbase + (size_t)(rowS + 64) * 1024 + k0 + kc * 8, &lB[(tid + 256) * 8]);
        __syncthreads();
        bf16x8 a[4], b[4];
#pragma unroll
        for (int i = 0; i < 4; i++) a[i] = *(const bf16x8*)&lA[(wm + i * 16 + l15) * 32 + quad * 8];
#pragma unroll
        for (int j = 0; j < 4; j++) b[j] = *(const bf16x8*)&lB[(wn + j * 16 + l15) * 32 + quad * 8];
#pragma unroll
        for (int i = 0; i < 4; i++)
#pragma unroll
            for (int j = 0; j < 4; j++)
                acc[i][j] = mfma16(a[i], b[j], acc[i][j]);
        __syncthreads();
    }
    int mat = n0 >> 10;
    int ncol0 = n0 & 1023;
    if (mat < 2) {
        __bf16* dst = (mat == 0) ? Qp : Kp;
        float sc = (mat == 0) ? 0.1803368801111204f : 1.0f;  // 0.125 * log2(e) for Q
#pragma unroll
        for (int i = 0; i < 4; i++) {
#pragma unroll
            for (int j = 0; j < 4; j++) {
                int n = ncol0 + wn + j * 16 + l15;
                int h = n >> 6, d = n & 63;
#pragma unroll
                for (int r = 0; r < 4; r++) {
                    int m = m0 + wm + i * 16 + quad * 4 + r;
                    int bb = m >> 11, s = m & 2047;
                    dst[((((size_t)bb * 16 + h) * 2048 + s) << 6) + d] = (__bf16)(acc[i][j][r] * sc);
                }
            }
        }
    } else {
        // V: transpose via LDS bounce -> Vt[((bb*16+h)*64 + d)*2048 + s]
#pragma unroll
        for (int i = 0; i < 4; i++)
#pragma unroll
            for (int j = 0; j < 4; j++)
#pragma unroll
                for (int r = 0; r < 4; r++)
                    lT[(wn + j * 16 + l15) * 136 + wm + i * 16 + quad * 4 + r] = (__bf16)acc[i][j][r];
        __syncthreads();
        int row = tid >> 1, c0 = (tid & 1) * 64;   // n_local 0..127, s-half
        int n = ncol0 + row;
        int hh = n >> 6, d = n & 63;
        int bb = m0 >> 11, s0 = (m0 & 2047) + c0;
        __bf16* dst = Vt + (((size_t)(bb * 16 + hh)) * 64 + d) * 2048 + s0;
#pragma unroll
        for (int e = 0; e < 8; e++)
            *(bf16x8*)(dst + e * 8) = *(const bf16x8*)&lT[row * 136 + c0 + e * 8];
    }
}

// ---------------------------------------------------------------- MFMA flash attention (R18)
// Grid 1024 (1D): bid = (bh&7) + 8*(qx + 16*(bh>>3)); qt = 15-qx (longest
// first; same bh -> same XCD -> K/V L2-resident). 4 waves x 32 q-rows.
// KV tile = 64 keys, double-buffered sK/sV (1 barrier/iter), V from Vt[B,H,64,S].
// Static-max base-2 softmax, l via MFMA-ones, sP (64 rows) per-h2 sequential.
__global__ __launch_bounds__(256, 3) void attn_kernel(
        const __bf16* __restrict__ Q, const __bf16* __restrict__ K,
        const __bf16* __restrict__ Vt, __bf16* __restrict__ ctx) {
    int bid = blockIdx.x;
    int xcd = bid & 7, t = bid >> 3;      // t 0..127
    int qx = t & 15;
    int bh = xcd + ((t >> 4) << 3);       // 0..63
    int qt = 15 - qx;                     // longest first
    int b = bh >> 4, h = bh & 15;
    const __bf16* Qb = Q  + (size_t)bh * (2048 * 64);
    const __bf16* Kb = K  + (size_t)bh * (2048 * 64);
    const __bf16* Vb = Vt + (size_t)bh * (64 * 2048);   // [d][s]
    __shared__ __bf16 sK[2][64 * 72];   // [key][d]
    __shared__ __bf16 sV[2][64 * 72];   // [d][key]
    __shared__ __bf16 sP[64 * 72];      // [q(16/wave)][key, group^quad], per h2
    int tid = threadIdx.x, w = tid >> 6, lane = tid & 63, quad = lane >> 4, l15 = lane & 15;
    int srow = tid >> 2, scol = tid & 3;   // K staging: key=srow, d0=scol*16
    int vd = tid >> 2, vc = tid & 3;       // V staging: d=vd, key0=vc*16
    const bf16x8 vone = { (__bf16)1.0f, (__bf16)1.0f, (__bf16)1.0f, (__bf16)1.0f,
                          (__bf16)1.0f, (__bf16)1.0f, (__bf16)1.0f, (__bf16)1.0f };

    int q0 = qt * 128;
    int nkt = 2 * qt + 2;
    bf16x8 aQ[2][2];
#pragma unroll
    for (int h2 = 0; h2 < 2; h2++)
#pragma unroll
        for (int c = 0; c < 2; c++)
            aQ[h2][c] = *(const bf16x8*)(Qb + (size_t)(q0 + w * 32 + h2 * 16 + l15) * 64 + c * 32 + quad * 8);
    f32x4 o[2][4] = {};
    f32x4 lac[2] = {};
    // prologue: stage tile 0 into buf 0
    {
        const __bf16* kp = Kb + srow * 64 + scol * 16;
        const __bf16* vp = Vb + (size_t)vd * 2048 + vc * 16;
        bf16x8 kA = *(const bf16x8*)kp;
        bf16x8 kB = *(const bf16x8*)(kp + 8);
        bf16x8 vA = *(const bf16x8*)vp;
        bf16x8 vB = *(const bf16x8*)(vp + 8);
        *(bf16x8*)&sK[0][srow * 72 + scol * 16]     = kA;
        *(bf16x8*)&sK[0][srow * 72 + scol * 16 + 8] = kB;
        *(bf16x8*)&sV[0][vd * 72 + vc * 16]         = vA;
        *(bf16x8*)&sV[0][vd * 72 + vc * 16 + 8]     = vB;
    }
    for (int kt = 0; kt < nkt; kt++) {
        int cur = kt & 1;
        __syncthreads();            // buf[cur] staged & visible
        bf16x8 kA, kB, vA, vB;
        if (kt + 1 < nkt) {         // T14: issue next-tile loads now
            const __bf16* kp = Kb + ((kt + 1) * 64 + srow) * 64 + scol * 16;
            const __bf16* vp = Vb + (size_t)vd * 2048 + (kt + 1) * 64 + vc * 16;
            kA = *(const bf16x8*)kp;  kB = *(const bf16x8*)(kp + 8);
            vA = *(const bf16x8*)vp;  vB = *(const bf16x8*)(vp + 8);
        }
        int mb = kt * 64 - q0;
        bool diag = (kt >= 2 * qt);
        if (!(diag && (mb - w * 32 >= 32))) {   // skip fully-masked waves
            // ---- QK^T
            f32x4 s[2][4] = {};
            __builtin_amdgcn_s_setprio(1);
#pragma unroll
            for (int c = 0; c < 2; c++)
#pragma unroll
                for (int j = 0; j < 4; j++) {
                    bf16x8 kf = *(const bf16x8*)&sK[cur][(j * 16 + l15) * 72 + c * 32 + quad * 8];
                    s[0][j] = mfma16(aQ[0][c], kf, s[0][j]);
                    s[1][j] = mfma16(aQ[1][c], kf, s[1][j]);
                }
            __builtin_amdgcn_s_setprio(0);
            if (diag && (mb + 63 > w * 32)) {
#pragma unroll
                for (int h2 = 0; h2 < 2; h2++)
#pragma unroll
                    for (int j = 0; j < 4; j++) {
                        int key = j * 16 + l15 + mb;
#pragma unroll
                        for (int r = 0; r < 4; r++)
                            if (key > w * 32 + h2 * 16 + quad * 4 + r) s[h2][j][r] = -1e30f;
                    }
            }
            // ---- static-max softmax: p = exp2(s)
#pragma unroll
            for (int h2 = 0; h2 < 2; h2++)
#pragma unroll
                for (int j = 0; j < 4; j++)
#pragma unroll
                    for (int r = 0; r < 4; r++)
                        s[h2][j][r] = exp2f(s[h2][j][r]);
            // ---- V fragments once (shared across h2)
            bf16x8 vv0[4], vv1[4];
#pragma unroll
            for (int dj = 0; dj < 4; dj++) {
                int vrow = (dj * 16 + l15) * 72;
                vv0[dj] = *(const bf16x8*)&sV[cur][vrow + quad * 8];
                vv1[dj] = *(const bf16x8*)&sV[cur][vrow + quad * 8 + 32];
            }
            // ---- per h2: P -> LDS (swizzled) -> PV + l (wave-private rows)
            int pswz = (l15 >> 2) << 4;
#pragma unroll
            for (int h2 = 0; h2 < 2; h2++) {
#pragma unroll
                for (int j = 0; j < 4; j++) {
                    int kg = ((j ^ quad) << 4) + l15;
#pragma unroll
                    for (int r = 0; r < 4; r++)
                        sP[(w * 16 + quad * 4 + r) * 72 + kg] = (__bf16)s[h2][j][r];
                }
                int prow = (w * 16 + l15) * 72;
                bf16x8 p0 = *(const bf16x8*)&sP[prow + ((quad * 8) ^ pswz)];
                bf16x8 p1 = *(const bf16x8*)&sP[prow + ((quad * 8 + 32) ^ pswz)];
                __builtin_amdgcn_s_setprio(1);
                lac[h2] = mfma16(p0, vone, lac[h2]);
                lac[h2] = mfma16(p1, vone, lac[h2]);
#pragma unroll
                for (int dj = 0; dj < 4; dj++) {
                    f32x4 tt = mfma16(p0, vv0[dj], o[h2][dj]);
                    o[h2][dj] = mfma16(p1, vv1[dj], tt);
                }
                __builtin_amdgcn_s_setprio(0);
            }
        }
        if (kt + 1 < nkt) {         // stage next tile into the other buffer
            *(bf16x8*)&sK[1 - cur][srow * 72 + scol * 16]     = kA;
            *(bf16x8*)&sK[1 - cur][srow * 72 + scol * 16 + 8] = kB;
            *(bf16x8*)&sV[1 - cur][vd * 72 + vc * 16]         = vA;
            *(bf16x8*)&sV[1 - cur][vd * 72 + vc * 16 + 8]     = vB;
        }
    }
    // epilogue
#pragma unroll
    for (int h2 = 0; h2 < 2; h2++)
#pragma unroll
        for (int r = 0; r < 4; r++) {
            float inv = 1.0f / lac[h2][r];
            int q = q0 + w * 32 + h2 * 16 + quad * 4 + r;
            size_t base = (((size_t)b * 2048 + q) << 10) + h * 64;
#pragma unroll
            for (int dj = 0; dj < 4; dj++)
                ctx[base + dj * 16 + l15] = (__bf16)(o[h2][dj][r] * inv);
        }
}

// ---------------------------------------------------------------- output GEMM (MFMA, fp32 bias+out)
__global__ __launch_bounds__(256, 2) void gemm_out_kernel(
        const __bf16* __restrict__ A, const __bf16* __restrict__ Bt,
        const float* __restrict__ bo, float* __restrict__ out) {
    __shared__ __bf16 lA[128 * 32];
    __shared__ __bf16 lB[128 * 32];
    int tid = threadIdx.x;
    int m0 = blockIdx.x * 128, n0 = blockIdx.y * 128;
    int w = tid >> 6, lane = tid & 63, quad = lane >> 4, l15 = lane & 15;
    int wm = (w & 1) * 64, wn = (w >> 1) * 64;
    f32x4 acc[4][4] = {};
    int rowS = tid >> 2, kc = tid & 3;
    const __bf16* Abase = A + (size_t)m0 * 1024;
    const __bf16* Bbase = Bt + (size_t)n0 * 1024;
    for (int kt = 0; kt < 32; kt++) {
        int k0 = kt * 32;
        gload16(Abase + (size_t)rowS * 1024 + k0 + kc * 8,        &lA[tid * 8]);
        gload16(Abase + (size_t)(rowS + 64) * 1024 + k0 + kc * 8, &lA[(tid + 256) * 8]);
        gload16(Bbase + (size_t)rowS * 1024 + k0 + kc * 8,        &lB[tid * 8]);
        gload16(Bbase + (size_t)(rowS + 64) * 1024 + k0 + kc * 8, &lB[(tid + 256) * 8]);
        __syncthreads();
        bf16x8 a[4], b[4];
#pragma unroll
        for (int i = 0; i < 4; i++) a[i] = *(const bf16x8*)&lA[(wm + i * 16 + l15) * 32 + quad * 8];
#pragma unroll
        for (int j = 0; j < 4; j++) b[j] = *(const bf16x8*)&lB[(wn + j * 16 + l15) * 32 + quad * 8];
#pragma unroll
        for (int i = 0; i < 4; i++)
#pragma unroll
            for (int j = 0; j < 4; j++)
                acc[i][j] = mfma16(a[i], b[j], acc[i][j]);
        __syncthreads();
    }
#pragma unroll
    for (int j = 0; j < 4; j++) {
        int n = n0 + wn + j * 16 + l15;
        float bias = bo[n];
#pragma unroll
        for (int i = 0; i < 4; i++)
#pragma unroll
            for (int r = 0; r < 4; r++) {
                int m = m0 + wm + i * 16 + quad * 4 + r;
                out[(size_t)m * 1024 + n] = acc[i][j][r] + bias;
            }
    }
}

// ---------------------------------------------------------------- launch
extern "C" void kernel_launch(void* const* d_in, const int* in_sizes, int n_in,
                              void* d_out, int out_size, void* d_ws, size_t ws_size,
                              hipStream_t stream) {
    const float* x  = (const float*)d_in[0];
    const float* Wq = (const float*)d_in[1];
    const float* Wk = (const float*)d_in[2];
    const float* Wv = (const float*)d_in[3];
    const float* Wo = (const float*)d_in[4];
    const float* bo = (const float*)d_in[5];
    float* out = (float*)d_out;

    __bf16* ws    = (__bf16*)d_ws;
    __bf16* xb    = ws;                   // 8192*1024
    __bf16* wqkvt = xb + 8388608;         // 3*1024*1024
    __bf16* wot   = wqkvt + 3145728;      // 1024*1024
    __bf16* Qp    = wot + 1048576;        // [B,H,S,HD]
    __bf16* Kp    = Qp + 8388608;
    __bf16* Vt    = Kp + 8388608;         // [B,H,HD,S] (written directly by gemm_qkv)
    __bf16* ctx   = Vt + 8388608;         // [8192,1024]

    prep_kernel<<<12288, 256, 0, stream>>>((const float4*)x, xb, Wq, Wk, Wv, Wo, wqkvt, wot);
    gemm_qkv_kernel<<<dim3(64, 24), 256, 0, stream>>>(xb, wqkvt, Qp, Kp, Vt);
    attn_kernel<<<1024, 256, 0, stream>>>(Qp, Kp, Vt, ctx);
    gemm_out_kernel<<<dim3(64, 8), 256, 0, stream>>>(ctx, wot, bo, out);
}

// Round 9
// 250.016 us; speedup vs baseline: 1.1294x; 1.1294x over previous
//
#include <hip/hip_runtime.h>

// MHA fwd: B=4, S=2048, D_IN=D_OUT=1024, H=16, HD=64. fp32 in / fp32 out.
// R19 = R18 with the dispatch-order bug fixed:
//   - R18's decode grouped blocks by bh-octet, so the LAST 256 dispatched
//     blocks contained qt=15 long blocks -> serial tail (attn 88->109 regress)
//     even though XCD locality worked (FETCH 146->27MB).
//   - R19 decode: qx = bid>>6, bh = bid&63, qt = 15-qx. Globally longest-first
//     (first 64 blocks are all qt=15; last 256 are the shortest, filling the
//     drain). bid&7 == bh&7 preserved -> same-bh -> same XCD -> K/V L2-resident.
//   - everything else unchanged from R18 (3 blocks/CU, halved per-h2 sP, dbuf
//     K/V 1-barrier, static-max softmax, MFMA-l, T14 prefetch, setprio, fused
//     prep, V written transposed by gemm_qkv).

typedef float  f32x4  __attribute__((ext_vector_type(4)));
typedef __bf16 bf16x8 __attribute__((ext_vector_type(8)));
typedef __bf16 bf16x4 __attribute__((ext_vector_type(4)));

#define AS(n) __attribute__((address_space(n)))

__device__ __forceinline__ void gload16(const void* g, void* l) {
    __builtin_amdgcn_global_load_lds((const AS(1) void*)g, (AS(3) void*)l, 16, 0, 0);
}

__device__ __forceinline__ f32x4 mfma16(bf16x8 a, bf16x8 b, f32x4 c) {
    return __builtin_amdgcn_mfma_f32_16x16x32_bf16(a, b, c, 0, 0, 0);
}

// ---------------------------------------------------------------- prep: x->bf16 + W transpose
__global__ void prep_kernel(const float4* __restrict__ x, __bf16* __restrict__ xb,
                            const float* __restrict__ Wq, const float* __restrict__ Wk,
                            const float* __restrict__ Wv, const float* __restrict__ Wo,
                            __bf16* __restrict__ wqkvt, __bf16* __restrict__ wot) {
    __shared__ float tile[32][33];
    int bid = blockIdx.x, tid = threadIdx.x;
    if (bid < 8192) {
        int t = bid * 256 + tid;
        float4 v = x[t];
        bf16x4 o = { (__bf16)v.x, (__bf16)v.y, (__bf16)v.z, (__bf16)v.w };
        ((bf16x4*)xb)[t] = o;
        return;
    }
    int idx = bid - 8192;                 // 0..4095
    int z = idx >> 10, rest = idx & 1023;
    int by = rest >> 5, bx = rest & 31;
    const float* src; __bf16* dst;
    if (z == 0)      { src = Wq; dst = wqkvt; }
    else if (z == 1) { src = Wk; dst = wqkvt + 1048576; }
    else if (z == 2) { src = Wv; dst = wqkvt + 2097152; }
    else             { src = Wo; dst = wot; }
    int tx = tid & 31, ty = tid >> 5;     // 32 x 8
    int xcol = bx * 32 + tx;
    int y0 = by * 32;
#pragma unroll
    for (int i = ty; i < 32; i += 8) tile[i][tx] = src[(size_t)(y0 + i) * 1024 + xcol];
    __syncthreads();
    int xo = by * 32 + tx;                // col = k
    int yo0 = bx * 32;                    // row = n
#pragma unroll
    for (int i = ty; i < 32; i += 8) dst[(size_t)(yo0 + i) * 1024 + xo] = (__bf16)tile[tx][i];
}

// ---------------------------------------------------------------- QKV GEMM (MFMA)
// Writes Q(scaled)/K as [B,H,S,HD]; V directly TRANSPOSED as Vt[B,H,HD,S].
__global__ __launch_bounds__(256, 2) void gemm_qkv_kernel(
        const __bf16* __restrict__ A, const __bf16* __restrict__ Bt,
        __bf16* __restrict__ Qp, __bf16* __restrict__ Kp, __bf16* __restrict__ Vt) {
    __shared__ __bf16 lA[128 * 32];
    __shared__ __bf16 lB[128 * 32];
    __shared__ __bf16 lT[128 * 136];   // V transpose bounce [n_local][m_local]
    int tid = threadIdx.x;
    int m0 = blockIdx.x * 128, n0 = blockIdx.y * 128;
    int w = tid >> 6, lane = tid & 63, quad = lane >> 4, l15 = lane & 15;
    int wm = (w & 1) * 64, wn = (w >> 1) * 64;
    f32x4 acc[4][4] = {};
    int rowS = tid >> 2, kc = tid & 3;
    const __bf16* Abase = A + (size_t)m0 * 1024;
    const __bf16* Bbase = Bt + (size_t)n0 * 1024;
    for (int kt = 0; kt < 32; kt++) {
        int k0 = kt * 32;
        gload16(Abase + (size_t)rowS * 1024 + k0 + kc * 8,        &lA[tid * 8]);
        gload16(Abase + (size_t)(rowS + 64) * 1024 + k0 + kc * 8, &lA[(tid + 256) * 8]);
        gload16(Bbase + (size_t)rowS * 1024 + k0 + kc * 8,        &lB[tid * 8]);
        gload16(Bbase + (size_t)(rowS + 64) * 1024 + k0 + kc * 8, &lB[(tid + 256) * 8]);
        __syncthreads();
        bf16x8 a[4], b[4];
#pragma unroll
        for (int i = 0; i < 4; i++) a[i] = *(const bf16x8*)&lA[(wm + i * 16 + l15) * 32 + quad * 8];
#pragma unroll
        for (int j = 0; j < 4; j++) b[j] = *(const bf16x8*)&lB[(wn + j * 16 + l15) * 32 + quad * 8];
#pragma unroll
        for (int i = 0; i < 4; i++)
#pragma unroll
            for (int j = 0; j < 4; j++)
                acc[i][j] = mfma16(a[i], b[j], acc[i][j]);
        __syncthreads();
    }
    int mat = n0 >> 10;
    int ncol0 = n0 & 1023;
    if (mat < 2) {
        __bf16* dst = (mat == 0) ? Qp : Kp;
        float sc = (mat == 0) ? 0.1803368801111204f : 1.0f;  // 0.125 * log2(e) for Q
#pragma unroll
        for (int i = 0; i < 4; i++) {
#pragma unroll
            for (int j = 0; j < 4; j++) {
                int n = ncol0 + wn + j * 16 + l15;
                int h = n >> 6, d = n & 63;
#pragma unroll
                for (int r = 0; r < 4; r++) {
                    int m = m0 + wm + i * 16 + quad * 4 + r;
                    int bb = m >> 11, s = m & 2047;
                    dst[((((size_t)bb * 16 + h) * 2048 + s) << 6) + d] = (__bf16)(acc[i][j][r] * sc);
                }
            }
        }
    } else {
        // V: transpose via LDS bounce -> Vt[((bb*16+h)*64 + d)*2048 + s]
#pragma unroll
        for (int i = 0; i < 4; i++)
#pragma unroll
            for (int j = 0; j < 4; j++)
#pragma unroll
                for (int r = 0; r < 4; r++)
                    lT[(wn + j * 16 + l15) * 136 + wm + i * 16 + quad * 4 + r] = (__bf16)acc[i][j][r];
        __syncthreads();
        int row = tid >> 1, c0 = (tid & 1) * 64;   // n_local 0..127, s-half
        int n = ncol0 + row;
        int hh = n >> 6, d = n & 63;
        int bb = m0 >> 11, s0 = (m0 & 2047) + c0;
        __bf16* dst = Vt + (((size_t)(bb * 16 + hh)) * 64 + d) * 2048 + s0;
#pragma unroll
        for (int e = 0; e < 8; e++)
            *(bf16x8*)(dst + e * 8) = *(const bf16x8*)&lT[row * 136 + c0 + e * 8];
    }
}

// ---------------------------------------------------------------- MFMA flash attention (R19)
// Grid 1024 (1D): qx = bid>>6 (ascending => qt=15-qx descending, globally
// longest-first); bh = bid&63 (bid&7 == bh&7 -> same bh -> same XCD -> K/V
// L2-resident). 4 waves x 32 q-rows. KV tile = 64 keys, double-buffered sK/sV
// (1 barrier/iter), V from Vt[B,H,64,S]. Static-max base-2 softmax, l via
// MFMA-ones, sP (64 rows) per-h2 sequential.
__global__ __launch_bounds__(256, 3) void attn_kernel(
        const __bf16* __restrict__ Q, const __bf16* __restrict__ K,
        const __bf16* __restrict__ Vt, __bf16* __restrict__ ctx) {
    int bid = blockIdx.x;
    int qx = bid >> 6;                    // 0..15
    int bh = bid & 63;                    // 0..63
    int qt = 15 - qx;                     // longest first, globally
    int b = bh >> 4, h = bh & 15;
    const __bf16* Qb = Q  + (size_t)bh * (2048 * 64);
    const __bf16* Kb = K  + (size_t)bh * (2048 * 64);
    const __bf16* Vb = Vt + (size_t)bh * (64 * 2048);   // [d][s]
    __shared__ __bf16 sK[2][64 * 72];   // [key][d]
    __shared__ __bf16 sV[2][64 * 72];   // [d][key]
    __shared__ __bf16 sP[64 * 72];      // [q(16/wave)][key, group^quad], per h2
    int tid = threadIdx.x, w = tid >> 6, lane = tid & 63, quad = lane >> 4, l15 = lane & 15;
    int srow = tid >> 2, scol = tid & 3;   // K staging: key=srow, d0=scol*16
    int vd = tid >> 2, vc = tid & 3;       // V staging: d=vd, key0=vc*16
    const bf16x8 vone = { (__bf16)1.0f, (__bf16)1.0f, (__bf16)1.0f, (__bf16)1.0f,
                          (__bf16)1.0f, (__bf16)1.0f, (__bf16)1.0f, (__bf16)1.0f };

    int q0 = qt * 128;
    int nkt = 2 * qt + 2;
    bf16x8 aQ[2][2];
#pragma unroll
    for (int h2 = 0; h2 < 2; h2++)
#pragma unroll
        for (int c = 0; c < 2; c++)
            aQ[h2][c] = *(const bf16x8*)(Qb + (size_t)(q0 + w * 32 + h2 * 16 + l15) * 64 + c * 32 + quad * 8);
    f32x4 o[2][4] = {};
    f32x4 lac[2] = {};
    // prologue: stage tile 0 into buf 0
    {
        const __bf16* kp = Kb + srow * 64 + scol * 16;
        const __bf16* vp = Vb + (size_t)vd * 2048 + vc * 16;
        bf16x8 kA = *(const bf16x8*)kp;
        bf16x8 kB = *(const bf16x8*)(kp + 8);
        bf16x8 vA = *(const bf16x8*)vp;
        bf16x8 vB = *(const bf16x8*)(vp + 8);
        *(bf16x8*)&sK[0][srow * 72 + scol * 16]     = kA;
        *(bf16x8*)&sK[0][srow * 72 + scol * 16 + 8] = kB;
        *(bf16x8*)&sV[0][vd * 72 + vc * 16]         = vA;
        *(bf16x8*)&sV[0][vd * 72 + vc * 16 + 8]     = vB;
    }
    for (int kt = 0; kt < nkt; kt++) {
        int cur = kt & 1;
        __syncthreads();            // buf[cur] staged & visible
        bf16x8 kA, kB, vA, vB;
        if (kt + 1 < nkt) {         // T14: issue next-tile loads now
            const __bf16* kp = Kb + ((kt + 1) * 64 + srow) * 64 + scol * 16;
            const __bf16* vp = Vb + (size_t)vd * 2048 + (kt + 1) * 64 + vc * 16;
            kA = *(const bf16x8*)kp;  kB = *(const bf16x8*)(kp + 8);
            vA = *(const bf16x8*)vp;  vB = *(const bf16x8*)(vp + 8);
        }
        int mb = kt * 64 - q0;
        bool diag = (kt >= 2 * qt);
        if (!(diag && (mb - w * 32 >= 32))) {   // skip fully-masked waves
            // ---- QK^T
            f32x4 s[2][4] = {};
            __builtin_amdgcn_s_setprio(1);
#pragma unroll
            for (int c = 0; c < 2; c++)
#pragma unroll
                for (int j = 0; j < 4; j++) {
                    bf16x8 kf = *(const bf16x8*)&sK[cur][(j * 16 + l15) * 72 + c * 32 + quad * 8];
                    s[0][j] = mfma16(aQ[0][c], kf, s[0][j]);
                    s[1][j] = mfma16(aQ[1][c], kf, s[1][j]);
                }
            __builtin_amdgcn_s_setprio(0);
            if (diag && (mb + 63 > w * 32)) {
#pragma unroll
                for (int h2 = 0; h2 < 2; h2++)
#pragma unroll
                    for (int j = 0; j < 4; j++) {
                        int key = j * 16 + l15 + mb;
#pragma unroll
                        for (int r = 0; r < 4; r++)
                            if (key > w * 32 + h2 * 16 + quad * 4 + r) s[h2][j][r] = -1e30f;
                    }
            }
            // ---- static-max softmax: p = exp2(s)
#pragma unroll
            for (int h2 = 0; h2 < 2; h2++)
#pragma unroll
                for (int j = 0; j < 4; j++)
#pragma unroll
                    for (int r = 0; r < 4; r++)
                        s[h2][j][r] = exp2f(s[h2][j][r]);
            // ---- V fragments once (shared across h2)
            bf16x8 vv0[4], vv1[4];
#pragma unroll
            for (int dj = 0; dj < 4; dj++) {
                int vrow = (dj * 16 + l15) * 72;
                vv0[dj] = *(const bf16x8*)&sV[cur][vrow + quad * 8];
                vv1[dj] = *(const bf16x8*)&sV[cur][vrow + quad * 8 + 32];
            }
            // ---- per h2: P -> LDS (swizzled) -> PV + l (wave-private rows)
            int pswz = (l15 >> 2) << 4;
#pragma unroll
            for (int h2 = 0; h2 < 2; h2++) {
#pragma unroll
                for (int j = 0; j < 4; j++) {
                    int kg = ((j ^ quad) << 4) + l15;
#pragma unroll
                    for (int r = 0; r < 4; r++)
                        sP[(w * 16 + quad * 4 + r) * 72 + kg] = (__bf16)s[h2][j][r];
                }
                int prow = (w * 16 + l15) * 72;
                bf16x8 p0 = *(const bf16x8*)&sP[prow + ((quad * 8) ^ pswz)];
                bf16x8 p1 = *(const bf16x8*)&sP[prow + ((quad * 8 + 32) ^ pswz)];
                __builtin_amdgcn_s_setprio(1);
                lac[h2] = mfma16(p0, vone, lac[h2]);
                lac[h2] = mfma16(p1, vone, lac[h2]);
#pragma unroll
                for (int dj = 0; dj < 4; dj++) {
                    f32x4 tt = mfma16(p0, vv0[dj], o[h2][dj]);
                    o[h2][dj] = mfma16(p1, vv1[dj], tt);
                }
                __builtin_amdgcn_s_setprio(0);
            }
        }
        if (kt + 1 < nkt) {         // stage next tile into the other buffer
            *(bf16x8*)&sK[1 - cur][srow * 72 + scol * 16]     = kA;
            *(bf16x8*)&sK[1 - cur][srow * 72 + scol * 16 + 8] = kB;
            *(bf16x8*)&sV[1 - cur][vd * 72 + vc * 16]         = vA;
            *(bf16x8*)&sV[1 - cur][vd * 72 + vc * 16 + 8]     = vB;
        }
    }
    // epilogue
#pragma unroll
    for (int h2 = 0; h2 < 2; h2++)
#pragma unroll
        for (int r = 0; r < 4; r++) {
            float inv = 1.0f / lac[h2][r];
            int q = q0 + w * 32 + h2 * 16 + quad * 4 + r;
            size_t base = (((size_t)b * 2048 + q) << 10) + h * 64;
#pragma unroll
            for (int dj = 0; dj < 4; dj++)
                ctx[base + dj * 16 + l15] = (__bf16)(o[h2][dj][r] * inv);
        }
}

// ---------------------------------------------------------------- output GEMM (MFMA, fp32 bias+out)
__global__ __launch_bounds__(256, 2) void gemm_out_kernel(
        const __bf16* __restrict__ A, const __bf16* __restrict__ Bt,
        const float* __restrict__ bo, float* __restrict__ out) {
    __shared__ __bf16 lA[128 * 32];
    __shared__ __bf16 lB[128 * 32];
    int tid = threadIdx.x;
    int m0 = blockIdx.x * 128, n0 = blockIdx.y * 128;
    int w = tid >> 6, lane = tid & 63, quad = lane >> 4, l15 = lane & 15;
    int wm = (w & 1) * 64, wn = (w >> 1) * 64;
    f32x4 acc[4][4] = {};
    int rowS = tid >> 2, kc = tid & 3;
    const __bf16* Abase = A + (size_t)m0 * 1024;
    const __bf16* Bbase = Bt + (size_t)n0 * 1024;
    for (int kt = 0; kt < 32; kt++) {
        int k0 = kt * 32;
        gload16(Abase + (size_t)rowS * 1024 + k0 + kc * 8,        &lA[tid * 8]);
        gload16(Abase + (size_t)(rowS + 64) * 1024 + k0 + kc * 8, &lA[(tid + 256) * 8]);
        gload16(Bbase + (size_t)rowS * 1024 + k0 + kc * 8,        &lB[tid * 8]);
        gload16(Bbase + (size_t)(rowS + 64) * 1024 + k0 + kc * 8, &lB[(tid + 256) * 8]);
        __syncthreads();
        bf16x8 a[4], b[4];
#pragma unroll
        for (int i = 0; i < 4; i++) a[i] = *(const bf16x8*)&lA[(wm + i * 16 + l15) * 32 + quad * 8];
#pragma unroll
        for (int j = 0; j < 4; j++) b[j] = *(const bf16x8*)&lB[(wn + j * 16 + l15) * 32 + quad * 8];
#pragma unroll
        for (int i = 0; i < 4; i++)
#pragma unroll
            for (int j = 0; j < 4; j++)
                acc[i][j] = mfma16(a[i], b[j], acc[i][j]);
        __syncthreads();
    }
#pragma unroll
    for (int j = 0; j < 4; j++) {
        int n = n0 + wn + j * 16 + l15;
        float bias = bo[n];
#pragma unroll
        for (int i = 0; i < 4; i++)
#pragma unroll
            for (int r = 0; r < 4; r++) {
                int m = m0 + wm + i * 16 + quad * 4 + r;
                out[(size_t)m * 1024 + n] = acc[i][j][r] + bias;
            }
    }
}

// ---------------------------------------------------------------- launch
extern "C" void kernel_launch(void* const* d_in, const int* in_sizes, int n_in,
                              void* d_out, int out_size, void* d_ws, size_t ws_size,
                              hipStream_t stream) {
    const float* x  = (const float*)d_in[0];
    const float* Wq = (const float*)d_in[1];
    const float* Wk = (const float*)d_in[2];
    const float* Wv = (const float*)d_in[3];
    const float* Wo = (const float*)d_in[4];
    const float* bo = (const float*)d_in[5];
    float* out = (float*)d_out;

    __bf16* ws    = (__bf16*)d_ws;
    __bf16* xb    = ws;                   // 8192*1024
    __bf16* wqkvt = xb + 8388608;         // 3*1024*1024
    __bf16* wot   = wqkvt + 3145728;      // 1024*1024
    __bf16* Qp    = wot + 1048576;        // [B,H,S,HD]
    __bf16* Kp    = Qp + 8388608;
    __bf16* Vt    = Kp + 8388608;         // [B,H,HD,S] (written directly by gemm_qkv)
    __bf16* ctx   = Vt + 8388608;         // [8192,1024]

    prep_kernel<<<12288, 256, 0, stream>>>((const float4*)x, xb, Wq, Wk, Wv, Wo, wqkvt, wot);
    gemm_qkv_kernel<<<dim3(64, 24), 256, 0, stream>>>(xb, wqkvt, Qp, Kp, Vt);
    attn_kernel<<<1024, 256, 0, stream>>>(Qp, Kp, Vt, ctx);
    gemm_out_kernel<<<dim3(64, 8), 256, 0, stream>>>(ctx, wot, bo, out);
}